// Round 4
// baseline (500.582 us; speedup 1.0000x reference)
//
#include <hip/hip_runtime.h>
#include <hip/hip_bf16.h>

#define NBANDS 31
#define CDIM 128
#define TDIM 2000
#define HDIM 512
#define MTOT 8000
#define MAXO 204
#define OPAD 224
#define NGRP 124
#define NMT 63
#define NWG (NBANDS * NMT)
#define NMTILE 504     // padded 16-row m-tiles per band (63*8 = 504 >= 500)

typedef __attribute__((ext_vector_type(8))) short short8;
typedef __attribute__((ext_vector_type(4))) float f32x4;
typedef __attribute__((ext_vector_type(4))) unsigned int u32x4;
typedef __bf16 bf16x8 __attribute__((ext_vector_type(8)));

__constant__ int d_bw[NBANDS]   = {2,3,3,3,3,3,3,3,3,3,3,8,8,8,8,8,8,8,8,8,8,8,8,16,16,16,16,16,16,16,17};
__constant__ int d_boff[NBANDS] = {0,2,5,8,11,14,17,20,23,26,29,32,40,48,56,64,72,80,88,96,104,112,120,128,144,160,176,192,208,224,240};
__constant__ int d_nn16[NBANDS] = {2,3,3,3,3,3,3,3,3,3,3,6,6,6,6,6,6,6,6,6,6,6,6,12,12,12,12,12,12,12,13};

__device__ __forceinline__ unsigned short f2bf(float f) {
  unsigned int u = __float_as_uint(f);
  return (unsigned short)((u + 0x7fffu + ((u >> 16) & 1u)) >> 16);
}

__device__ __forceinline__ float fast_tanh(float x) {
  float e = __expf(2.0f * fabsf(x));
  float t = 1.0f - 2.0f / (e + 1.0f);
  return copysignf(t, x);
}

__device__ __forceinline__ float fast_sigmoid(float x) {
  return 1.0f / (1.0f + __expf(-x));
}

__device__ __forceinline__ f32x4 mfma_bf16(short8 a, short8 b, f32x4 c) {
  return __builtin_amdgcn_mfma_f32_16x16x32_bf16(
      __builtin_bit_cast(bf16x8, a), __builtin_bit_cast(bf16x8, b), c, 0, 0, 0);
}

// ------------- finalize group stats -------------
__global__ void k_finalize(const float* __restrict__ wsum, const float* __restrict__ wsq,
                           float* __restrict__ gmean, float* __restrict__ grstd) {
  int g = threadIdx.x;
  if (g < NGRP) {
    const float n = (float)(CDIM * TDIM);
    float m = wsum[g] / n;
    float v = wsq[g] / n - m * m;
    gmean[g] = m;
    grstd[g] = rsqrtf(v + 1e-5f);
  }
}

// ------------- prep fc1: fold norm affine, write MFMA-A fragment order ------
// w1f layout: [k][nc 4][hh 8][kk 4][lane 64][8e]; lane l holds
//   W1fold[h = nc*128 + hh*16 + (l&15)][c = kk*32 + (l>>4)*8 + j]
__global__ void k_prep_w1(const float* __restrict__ fc1_w, const float* __restrict__ norm_w,
                          const float* __restrict__ norm_b, const float* __restrict__ fc1_b,
                          unsigned short* __restrict__ w1f, float* __restrict__ t1,
                          float* __restrict__ t2) {
  int kn = blockIdx.x;              // k*512 + n(h)
  int k = kn >> 9, n = kn & 511;
  int c = threadIdx.x;              // 128 threads
  float w  = fc1_w[(size_t)kn * CDIM + c];
  float nw = norm_w[k * CDIM + c];
  float nb = norm_b[k * CDIM + c];
  float wp = w * nw;
  {
    int nc = n >> 7, hh = (n >> 4) & 7, kk = c >> 5;
    int lnw = (n & 15) | (((c >> 3) & 3) << 4);
    size_t eoff = ((((size_t)(k * 4 + nc) * 8 + hh) * 4 + kk) * 64 + lnw) * 8 + (c & 7);
    w1f[eoff] = f2bf(wp);
  }
  float s1 = wp, s2 = w * nb;
  #pragma unroll
  for (int off = 32; off >= 1; off >>= 1) {
    s1 += __shfl_down(s1, off);
    s2 += __shfl_down(s2, off);
  }
  __shared__ float r1[2], r2[2];
  if ((threadIdx.x & 63) == 0) { r1[threadIdx.x >> 6] = s1; r2[threadIdx.x >> 6] = s2; }
  __syncthreads();
  if (threadIdx.x == 0) {
    t1[kn] = r1[0] + r1[1];
    t2[kn] = r2[0] + r2[1] + fc1_b[kn];
  }
}

// ------------- prep fc2: GLU-pair permute, MFMA-B fragment order ------------
// w2f layout: [k][nc 4][otile 14][kp 4][lane 64][8e]; lane l holds
//   W2perm[o = otile*16 + (l&15)][hc = nc*128 + kp*32 + (l>>4)*8 + j]
__global__ void k_prep_w2(const float* __restrict__ fc2_w, const float* __restrict__ fc2_b,
                          unsigned short* __restrict__ w2f, float* __restrict__ b2) {
  int ko = blockIdx.x;              // k*OPAD + o
  int k = ko / OPAD;
  int o = ko - k * OPAD;
  int bw = d_bw[k];
  int O2 = 12 * bw, hf = 6 * bw;
  int srcrow = (o & 1) ? (hf + (o >> 1)) : (o >> 1);
  bool valid = o < O2;
  const float* sp = fc2_w + ((size_t)k * MAXO + srcrow) * HDIM;
  if (threadIdx.x == 0) b2[ko] = valid ? fc2_b[k * MAXO + srcrow] : 0.f;
  for (int j = threadIdx.x; j < HDIM; j += 256) {
    int nc = j >> 7, jc = j & 127, kp = jc >> 5, q = (jc >> 3) & 3, jj = j & 7;
    int lnw = (o & 15) | (q << 4);
    unsigned short val = valid ? f2bf(sp[j]) : (unsigned short)0;
    size_t eoff = ((((size_t)(k * 4 + nc) * 14 + (o >> 4)) * 4 + kp) * 64 + lnw) * 8 + jj;
    w2f[eoff] = val;
  }
}

// ------------- transpose x[B,C,T,K] -> xtf fragment order, fused stats ------
// xtf layout: [k][mtile NMTILE][kk 4][lane 64][8e]; lane l holds
//   X[m = mtile*16 + (l&15)][c = kk*32 + (l>>4)*8 + j]
__global__ void k_transpose(const float* __restrict__ x, unsigned short* __restrict__ xtf,
                            float* __restrict__ wsum, float* __restrict__ wsq) {
  __shared__ unsigned short tile[248 * 128];   // rows staggered by 4f bytes
  __shared__ float sred[256], sqred[256];
  const int t0 = blockIdx.x * 8;
  const int b = blockIdx.y;
  const int tid = threadIdx.x;
  const float* p = x + ((size_t)b * CDIM * TDIM + t0) * NBANDS;
  float s = 0.f, sq = 0.f;
  if (tid < 248) {
    const int f = tid;
    char* row = (char*)tile + f * 256;
    const int st = 4 * f;
    #pragma unroll 4
    for (int c2 = 0; c2 < 64; ++c2) {
      float v0 = p[(size_t)c2 * 124000 + f];
      float v1 = p[(size_t)c2 * 124000 + 62000 + f];
      s += v0 + v1;
      sq += v0 * v0 + v1 * v1;
      unsigned int pk = (unsigned int)f2bf(v0) | ((unsigned int)f2bf(v1) << 16);
      *(unsigned int*)(row + ((4 * c2 + st) & 255)) = pk;
    }
  }
  sred[tid] = s; sqred[tid] = sq;
  __syncthreads();
  if (tid < 31) {
    float ss = 0.f, qs = 0.f;
    #pragma unroll
    for (int j = 0; j < 8; ++j) { ss += sred[tid + 31 * j]; qs += sqred[tid + 31 * j]; }
    atomicAdd(&wsum[b * 31 + tid], ss);
    atomicAdd(&wsq [b * 31 + tid], qs);
  }
  // write fragment-ordered, 128B coalesced runs (ti fastest)
  for (int idx = tid; idx < 3968; idx += 256) {
    int ti = idx & 7, q4w = (idx >> 3) & 3, kkw = (idx >> 5) & 3, kb = idx >> 7;
    int f = ti * 31 + kb;
    const char* row = (const char*)tile + f * 256;
    const int st = 4 * f;
    u32x4 v;
    #pragma unroll
    for (int j = 0; j < 4; ++j)
      v[j] = *(const unsigned int*)(row + ((kkw * 64 + q4w * 16 + 4 * j + st) & 255));
    int m = b * TDIM + t0 + ti;
    int mtile = m >> 4, mrow = m & 15;
    size_t eoff = ((((size_t)kb * NMTILE + mtile) * 4 + kkw) * 64 + (mrow | (q4w << 4))) * 8;
    *(u32x4*)(xtf + eoff) = v;
  }
}

// ------------- fused GEMM: fc1 + tanh + fc2 + GLU ---------------------------
__launch_bounds__(512, 4)
__global__ void k_gemm(const unsigned short* __restrict__ xtf,
                       const unsigned short* __restrict__ w1f,
                       const float* __restrict__ t1p, const float* __restrict__ t2p,
                       const unsigned short* __restrict__ w2f,
                       const float* __restrict__ b2p,
                       const float* __restrict__ gmean, const float* __restrict__ grstd,
                       float* __restrict__ out) {
  extern __shared__ char lds[];
  char* const HsA = lds;            // 32 KB [128 m][128 h] swizzled bf16
  char* const HsB = lds + 32768;    // 32 KB
  float* const Ls = (float*)lds;    // out-staging reuse (<= 52.2 KB)

  // bijective XCD-aware swizzle (nwg = 1953)
  const int bid = blockIdx.x;
  const int qq = NWG >> 3, r8 = NWG & 7;
  const int xcd = bid & 7, ixd = bid >> 3;
  const int wg = (xcd < r8 ? xcd * (qq + 1) : r8 * (qq + 1) + (xcd - r8) * qq) + ixd;
  const int k = wg / NMT;
  const int mt = wg - k * NMT;
  const int m0 = mt * 128;

  const int tid = threadIdx.x;
  const int lane = tid & 63;
  const int wid = tid >> 6;
  const int gm = wid & 1;     // m-half (64 rows)
  const int gh = wid >> 1;    // fc1 h-group / fc2 o-slot base
  const int col = lane & 15;
  const int q4 = lane >> 4;

  const int bw = d_bw[k];
  const int nn = d_nn16[k];
  const int half = 6 * bw;
  const int boffk = d_boff[k];

  // per-column norm constants (output col = token)
  float rs4[4], mn4[4];
  #pragma unroll
  for (int m4 = 0; m4 < 4; ++m4) {
    int mr = m0 + gm * 64 + m4 * 16 + col;
    int mc = mr < (MTOT - 1) ? mr : (MTOT - 1);
    int g = (mc / 2000) * NBANDS + k;
    rs4[m4] = grstd[g];
    mn4[m4] = gmean[g];
  }

  const f32x4 fz = {0.f, 0.f, 0.f, 0.f};
  f32x4 acc2[4][4];
  #pragma unroll
  for (int a = 0; a < 4; ++a)
    #pragma unroll
    for (int c = 0; c < 4; ++c) acc2[a][c] = fz;

  const size_t xbase = (((size_t)k * NMTILE + (m0 >> 4) + gm * 4) * 4) * 512 + (size_t)lane * 8;

  #pragma unroll 1
  for (int nc = 0; nc < 4; ++nc) {
    char* const Hc = (nc & 1) ? HsB : HsA;
    const unsigned short* w1b = w1f + (size_t)(k * 4 + nc) * 16384 + lane * 8;

    // ---- fc1 (swapped operands): acc1 = W1frag x Xfrag, all from global ----
    f32x4 acc1[4][2];
    #pragma unroll
    for (int a = 0; a < 4; ++a) { acc1[a][0] = fz; acc1[a][1] = fz; }

    #pragma unroll
    for (int kk = 0; kk < 4; ++kk) {
      short8 wa0 = *(const short8*)(w1b + (gh * 8 + kk) * 512);
      short8 wa1 = *(const short8*)(w1b + (gh * 8 + 4 + kk) * 512);
      #pragma unroll
      for (int m4 = 0; m4 < 4; ++m4) {
        short8 xv = *(const short8*)(xtf + xbase + (m4 * 4 + kk) * 512);
        acc1[m4][0] = mfma_bf16(wa0, xv, acc1[m4][0]);
        acc1[m4][1] = mfma_bf16(wa1, xv, acc1[m4][1]);
      }
    }

    // ---- fc1 epilogue: fold norm, tanh, pack 4 h -> b64 into Hc ----
    const float* t1k = t1p + k * HDIM + nc * 128;
    const float* t2k = t2p + k * HDIM + nc * 128;
    #pragma unroll
    for (int m4 = 0; m4 < 4; ++m4) {
      const int mloc = gm * 64 + m4 * 16 + col;
      const int swz = (mloc & 7) << 4;
      const float rsm = rs4[m4], rmn = rs4[m4] * mn4[m4];
      #pragma unroll
      for (int ht = 0; ht < 2; ++ht) {
        const int hb = gh * 32 + ht * 16 + q4 * 4;
        f32x4 c1 = *(const f32x4*)(t1k + hb);
        f32x4 c2 = *(const f32x4*)(t2k + hb);
        f32x4 v = acc1[m4][ht];
        float e0 = fast_tanh(rsm * v[0] - rmn * c1[0] + c2[0]);
        float e1 = fast_tanh(rsm * v[1] - rmn * c1[1] + c2[1]);
        float e2 = fast_tanh(rsm * v[2] - rmn * c1[2] + c2[2]);
        float e3 = fast_tanh(rsm * v[3] - rmn * c1[3] + c2[3]);
        unsigned long long pk =
            (unsigned long long)f2bf(e0) | ((unsigned long long)f2bf(e1) << 16) |
            ((unsigned long long)f2bf(e2) << 32) | ((unsigned long long)f2bf(e3) << 48);
        *(unsigned long long*)(Hc + mloc * 256 + ((2 * hb) ^ swz)) = pk;
      }
    }

    __syncthreads();   // Hc visible; HsA/HsB alternation makes 1 barrier/nc safe

    // ---- fc2 partial: acc2 += Hfrag x W2frag (W2 from global, frag order) ----
    const unsigned short* w2b = w2f + (size_t)(k * 4 + nc) * 28672 + lane * 8;
    #pragma unroll
    for (int kp = 0; kp < 4; ++kp) {
      const int cb = kp * 64 + q4 * 16;
      short8 ha[4];
      #pragma unroll
      for (int m4 = 0; m4 < 4; ++m4) {
        const int mloc = gm * 64 + m4 * 16 + col;
        ha[m4] = *(const short8*)(Hc + mloc * 256 + (cb ^ ((mloc & 7) << 4)));
      }
      #pragma unroll
      for (int s = 0; s < 4; ++s) {
        const int i = gh + 4 * s;
        if (i < nn) {
          short8 wb = *(const short8*)(w2b + (i * 4 + kp) * 512);
          #pragma unroll
          for (int m4 = 0; m4 < 4; ++m4)
            acc2[m4][s] = mfma_bf16(ha[m4], wb, acc2[m4][s]);
        }
      }
    }
  }

  // ---- output epilogue: bias, GLU via shfl_xor ----
  const float* b2k = b2p + (size_t)k * OPAD;
  const bool plain = ((m0 + 127) / 2000 == m0 / 2000) && (m0 + 128 <= MTOT);
  if (plain) {
    __syncthreads();   // all fc2 reads of Hs done before Ls overwrite
    #pragma unroll
    for (int s = 0; s < 4; ++s) {
      const int i = gh + 4 * s;
      if (i < nn) {
        const int o = i * 16 + col;
        const float bias = b2k[o];
        const bool isA = (o & 1) == 0;
        const int op = o >> 1;
        #pragma unroll
        for (int m4 = 0; m4 < 4; ++m4) {
          f32x4 v = acc2[m4][s];
          #pragma unroll
          for (int r2 = 0; r2 < 4; ++r2) {
            float val = v[r2] + bias;
            float other = __shfl_xor(val, 1);
            if (isA && op < half) {
              int tloc = gm * 64 + m4 * 16 + q4 * 4 + r2;
              int orr = op / 6;
              int occ = op - orr * 6;
              Ls[(orr * 128 + tloc) * 6 + occ] = val * fast_sigmoid(other);
            }
          }
        }
      }
    }
    __syncthreads();
    // coalesced store: per orr a contiguous 3072B run
    const int bb = m0 / 2000;
    const int tb = m0 - bb * 2000;
    const size_t obase = ((size_t)bb * 257 + boffk) * 2000;
    const int tot = bw * 384;          // u64 chunks
    for (int ii = tid; ii < tot; ii += 512) {
      int orr = ii / 384;
      int rem = ii - orr * 384;
      *(unsigned long long*)(out + (obase + (size_t)orr * 2000 + tb) * 6 + rem * 2) =
          *(const unsigned long long*)(Ls + orr * 768 + rem * 2);
    }
  } else {
    // boundary/tail tiles: scatter store
    #pragma unroll
    for (int s = 0; s < 4; ++s) {
      const int i = gh + 4 * s;
      if (i < nn) {
        const int o = i * 16 + col;
        const float bias = b2k[o];
        const bool isA = (o & 1) == 0;
        const int op = o >> 1;
        #pragma unroll
        for (int m4 = 0; m4 < 4; ++m4) {
          f32x4 v = acc2[m4][s];
          #pragma unroll
          for (int r2 = 0; r2 < 4; ++r2) {
            float val = v[r2] + bias;
            float other = __shfl_xor(val, 1);
            int m = m0 + gm * 64 + m4 * 16 + q4 * 4 + r2;
            if (isA && op < half && m < MTOT) {
              float res = val * fast_sigmoid(other);
              int bb = m / 2000;
              int t = m - bb * 2000;
              int orr = op / 6;
              int occ = op - orr * 6;
              out[(((size_t)bb * 257 + boffk + orr) * TDIM + t) * 6 + occ] = res;
            }
          }
        }
      }
    }
  }
}

extern "C" void kernel_launch(void* const* d_in, const int* in_sizes, int n_in,
                              void* d_out, int out_size, void* d_ws, size_t ws_size,
                              hipStream_t stream) {
  const float* x      = (const float*)d_in[0];
  const float* norm_w = (const float*)d_in[1];
  const float* norm_b = (const float*)d_in[2];
  const float* fc1_w  = (const float*)d_in[3];
  const float* fc1_b  = (const float*)d_in[4];
  const float* fc2_w  = (const float*)d_in[5];
  const float* fc2_b  = (const float*)d_in[6];
  float* out = (float*)d_out;
  char* ws = (char*)d_ws;

  float* wsum  = (float*)(ws);
  float* wsq   = (float*)(ws + 512);
  float* gmean = (float*)(ws + 1024);
  float* grstd = (float*)(ws + 1536);
  size_t off = 4096;
  unsigned short* xtf = (unsigned short*)(ws + off); off += (size_t)NBANDS * NMTILE * 4 * 512 * 2;
  unsigned short* w1f = (unsigned short*)(ws + off); off += (size_t)NBANDS * 4 * 8 * 4 * 512 * 2;
  float* t1p = (float*)(ws + off); off += (size_t)NBANDS * HDIM * 4;
  float* t2p = (float*)(ws + off); off += (size_t)NBANDS * HDIM * 4;
  unsigned short* w2f = (unsigned short*)(ws + off); off += (size_t)NBANDS * 4 * 14 * 4 * 512 * 2;
  float* b2p = (float*)(ws + off); off += (size_t)NBANDS * OPAD * 4;

  hipMemsetAsync(ws, 0, 1024, stream);
  hipLaunchKernelGGL(k_prep_w1, dim3(NBANDS * HDIM), dim3(128), 0, stream,
                     fc1_w, norm_w, norm_b, fc1_b, w1f, t1p, t2p);
  hipLaunchKernelGGL(k_prep_w2, dim3(NBANDS * OPAD), dim3(256), 0, stream,
                     fc2_w, fc2_b, w2f, b2p);
  hipLaunchKernelGGL(k_transpose, dim3(250, 4), dim3(256), 0, stream, x, xtf, wsum, wsq);
  hipLaunchKernelGGL(k_finalize, dim3(1), dim3(128), 0, stream, wsum, wsq, gmean, grstd);

  hipFuncSetAttribute((const void*)k_gemm, hipFuncAttributeMaxDynamicSharedMemorySize, 65536);
  hipLaunchKernelGGL(k_gemm, dim3(NWG), dim3(512), 65536, stream,
                     xtf, w1f, t1p, t2p, w2f, b2p, gmean, grstd, out);
}

// Round 5
// 320.880 us; speedup vs baseline: 1.5600x; 1.5600x over previous
//
#include <hip/hip_runtime.h>
#include <hip/hip_bf16.h>

#define NBANDS 31
#define CDIM 128
#define TDIM 2000
#define HDIM 512
#define MTOT 8000
#define MAXO 204
#define OPAD 224
#define NGRP 124
#define NMT 63
#define NWG (NBANDS * NMT)
#define NMTILE 504     // padded 16-row m-tiles per band (63*8 = 504 >= 500)

typedef __attribute__((ext_vector_type(8))) short short8;
typedef __attribute__((ext_vector_type(4))) float f32x4;
typedef __attribute__((ext_vector_type(4))) unsigned int u32x4;
typedef __bf16 bf16x8 __attribute__((ext_vector_type(8)));

__constant__ int d_bw[NBANDS]   = {2,3,3,3,3,3,3,3,3,3,3,8,8,8,8,8,8,8,8,8,8,8,8,16,16,16,16,16,16,16,17};
__constant__ int d_boff[NBANDS] = {0,2,5,8,11,14,17,20,23,26,29,32,40,48,56,64,72,80,88,96,104,112,120,128,144,160,176,192,208,224,240};
__constant__ int d_nn16[NBANDS] = {2,3,3,3,3,3,3,3,3,3,3,6,6,6,6,6,6,6,6,6,6,6,6,12,12,12,12,12,12,12,13};

__device__ __forceinline__ unsigned short f2bf(float f) {
  unsigned int u = __float_as_uint(f);
  return (unsigned short)((u + 0x7fffu + ((u >> 16) & 1u)) >> 16);
}

__device__ __forceinline__ float fast_tanh(float x) {
  float e = __expf(2.0f * fabsf(x));
  float t = 1.0f - 2.0f / (e + 1.0f);
  return copysignf(t, x);
}

__device__ __forceinline__ float fast_sigmoid(float x) {
  return 1.0f / (1.0f + __expf(-x));
}

__device__ __forceinline__ f32x4 mfma_bf16(short8 a, short8 b, f32x4 c) {
  return __builtin_amdgcn_mfma_f32_16x16x32_bf16(
      __builtin_bit_cast(bf16x8, a), __builtin_bit_cast(bf16x8, b), c, 0, 0, 0);
}

// ------------- finalize group stats -------------
__global__ void k_finalize(const float* __restrict__ wsum, const float* __restrict__ wsq,
                           float* __restrict__ gmean, float* __restrict__ grstd) {
  int g = threadIdx.x;
  if (g < NGRP) {
    const float n = (float)(CDIM * TDIM);
    float m = wsum[g] / n;
    float v = wsq[g] / n - m * m;
    gmean[g] = m;
    grstd[g] = rsqrtf(v + 1e-5f);
  }
}

// ------------- prep fc1: fold norm affine, write MFMA-A fragment order ------
// w1f layout: [k][nc 4][hh 8][kk 4][lane 64][8e]; lane l holds
//   W1fold[h = nc*128 + hh*16 + (l&15)][c = kk*32 + (l>>4)*8 + j]
__global__ void k_prep_w1(const float* __restrict__ fc1_w, const float* __restrict__ norm_w,
                          const float* __restrict__ norm_b, const float* __restrict__ fc1_b,
                          unsigned short* __restrict__ w1f, float* __restrict__ t1,
                          float* __restrict__ t2) {
  int kn = blockIdx.x;              // k*512 + n(h)
  int k = kn >> 9, n = kn & 511;
  int c = threadIdx.x;              // 128 threads
  float w  = fc1_w[(size_t)kn * CDIM + c];
  float nw = norm_w[k * CDIM + c];
  float nb = norm_b[k * CDIM + c];
  float wp = w * nw;
  {
    int nc = n >> 7, hh = (n >> 4) & 7, kk = c >> 5;
    int lnw = (n & 15) | (((c >> 3) & 3) << 4);
    size_t eoff = ((((size_t)(k * 4 + nc) * 8 + hh) * 4 + kk) * 64 + lnw) * 8 + (c & 7);
    w1f[eoff] = f2bf(wp);
  }
  float s1 = wp, s2 = w * nb;
  #pragma unroll
  for (int off = 32; off >= 1; off >>= 1) {
    s1 += __shfl_down(s1, off);
    s2 += __shfl_down(s2, off);
  }
  __shared__ float r1[2], r2[2];
  if ((threadIdx.x & 63) == 0) { r1[threadIdx.x >> 6] = s1; r2[threadIdx.x >> 6] = s2; }
  __syncthreads();
  if (threadIdx.x == 0) {
    t1[kn] = r1[0] + r1[1];
    t2[kn] = r2[0] + r2[1] + fc1_b[kn];
  }
}

// ------------- prep fc2: GLU-pair permute, MFMA-B fragment order ------------
// w2f layout: [k][nc 4][otile 14][kp 4][lane 64][8e]; lane l holds
//   W2perm[o = otile*16 + (l&15)][hc = nc*128 + kp*32 + (l>>4)*8 + j]
__global__ void k_prep_w2(const float* __restrict__ fc2_w, const float* __restrict__ fc2_b,
                          unsigned short* __restrict__ w2f, float* __restrict__ b2) {
  int ko = blockIdx.x;              // k*OPAD + o
  int k = ko / OPAD;
  int o = ko - k * OPAD;
  int bw = d_bw[k];
  int O2 = 12 * bw, hf = 6 * bw;
  int srcrow = (o & 1) ? (hf + (o >> 1)) : (o >> 1);
  bool valid = o < O2;
  const float* sp = fc2_w + ((size_t)k * MAXO + srcrow) * HDIM;
  if (threadIdx.x == 0) b2[ko] = valid ? fc2_b[k * MAXO + srcrow] : 0.f;
  for (int j = threadIdx.x; j < HDIM; j += 256) {
    int nc = j >> 7, jc = j & 127, kp = jc >> 5, q = (jc >> 3) & 3, jj = j & 7;
    int lnw = (o & 15) | (q << 4);
    unsigned short val = valid ? f2bf(sp[j]) : (unsigned short)0;
    size_t eoff = ((((size_t)(k * 4 + nc) * 14 + (o >> 4)) * 4 + kp) * 64 + lnw) * 8 + jj;
    w2f[eoff] = val;
  }
}

// ------------- transpose x[B,C,T,K] -> xtf fragment order, fused stats ------
// xtf layout: [k][mtile NMTILE][kk 4][lane 64][8e]; lane l holds
//   X[m = mtile*16 + (l&15)][c = kk*32 + (l>>4)*8 + j]
__global__ void k_transpose(const float* __restrict__ x, unsigned short* __restrict__ xtf,
                            float* __restrict__ wsum, float* __restrict__ wsq) {
  __shared__ unsigned short tile[248 * 128];   // rows staggered by 4f bytes
  __shared__ float sred[256], sqred[256];
  const int t0 = blockIdx.x * 8;
  const int b = blockIdx.y;
  const int tid = threadIdx.x;
  const float* p = x + ((size_t)b * CDIM * TDIM + t0) * NBANDS;
  float s = 0.f, sq = 0.f;
  if (tid < 248) {
    const int f = tid;
    char* row = (char*)tile + f * 256;
    const int st = 4 * f;
    #pragma unroll 4
    for (int c2 = 0; c2 < 64; ++c2) {
      float v0 = p[(size_t)c2 * 124000 + f];
      float v1 = p[(size_t)c2 * 124000 + 62000 + f];
      s += v0 + v1;
      sq += v0 * v0 + v1 * v1;
      unsigned int pk = (unsigned int)f2bf(v0) | ((unsigned int)f2bf(v1) << 16);
      *(unsigned int*)(row + ((4 * c2 + st) & 255)) = pk;
    }
  }
  sred[tid] = s; sqred[tid] = sq;
  __syncthreads();
  if (tid < 31) {
    float ss = 0.f, qs = 0.f;
    #pragma unroll
    for (int j = 0; j < 8; ++j) { ss += sred[tid + 31 * j]; qs += sqred[tid + 31 * j]; }
    atomicAdd(&wsum[b * 31 + tid], ss);
    atomicAdd(&wsq [b * 31 + tid], qs);
  }
  // write fragment-ordered, 128B coalesced runs (ti fastest)
  for (int idx = tid; idx < 3968; idx += 256) {
    int ti = idx & 7, q4w = (idx >> 3) & 3, kkw = (idx >> 5) & 3, kb = idx >> 7;
    int f = ti * 31 + kb;
    const char* row = (const char*)tile + f * 256;
    const int st = 4 * f;
    u32x4 v;
    #pragma unroll
    for (int j = 0; j < 4; ++j)
      v[j] = *(const unsigned int*)(row + ((kkw * 64 + q4w * 16 + 4 * j + st) & 255));
    int m = b * TDIM + t0 + ti;
    int mtile = m >> 4, mrow = m & 15;
    size_t eoff = ((((size_t)kb * NMTILE + mtile) * 4 + kkw) * 64 + (mrow | (q4w << 4))) * 8;
    *(u32x4*)(xtf + eoff) = v;
  }
}

// ------------- fused GEMM: fc1 + tanh + fc2 + GLU ---------------------------
// __launch_bounds__(512, 2): empirically caps VGPR at 128 (R3).  (512,4) caps
// at 64 and spills ~60 regs -> 520 MB scratch writes (R4 regression).
__launch_bounds__(512, 2)
__global__ void k_gemm(const unsigned short* __restrict__ xtf,
                       const unsigned short* __restrict__ w1f,
                       const float* __restrict__ t1p, const float* __restrict__ t2p,
                       const unsigned short* __restrict__ w2f,
                       const float* __restrict__ b2p,
                       const float* __restrict__ gmean, const float* __restrict__ grstd,
                       float* __restrict__ out) {
  extern __shared__ char lds[];
  char* const HsA = lds;            // 32 KB [128 m][128 h] swizzled bf16
  char* const HsB = lds + 32768;    // 32 KB
  float* const Ls = (float*)lds;    // out-staging reuse (<= 52.2 KB)

  // bijective XCD-aware swizzle (nwg = 1953)
  const int bid = blockIdx.x;
  const int qq = NWG >> 3, r8 = NWG & 7;
  const int xcd = bid & 7, ixd = bid >> 3;
  const int wg = (xcd < r8 ? xcd * (qq + 1) : r8 * (qq + 1) + (xcd - r8) * qq) + ixd;
  const int k = wg / NMT;
  const int mt = wg - k * NMT;
  const int m0 = mt * 128;

  const int tid = threadIdx.x;
  const int lane = tid & 63;
  const int wid = tid >> 6;
  const int gm = wid & 1;     // m-half (64 rows)
  const int gh = wid >> 1;    // fc1 h-group / fc2 o-slot base
  const int col = lane & 15;
  const int q4 = lane >> 4;

  const int bw = d_bw[k];
  const int nn = d_nn16[k];
  const int half = 6 * bw;
  const int boffk = d_boff[k];

  // per-column norm constants (output col = token)
  float rs4[4], mn4[4];
  #pragma unroll
  for (int m4 = 0; m4 < 4; ++m4) {
    int mr = m0 + gm * 64 + m4 * 16 + col;
    int mc = mr < (MTOT - 1) ? mr : (MTOT - 1);
    int g = (mc / 2000) * NBANDS + k;
    rs4[m4] = grstd[g];
    mn4[m4] = gmean[g];
  }

  const f32x4 fz = {0.f, 0.f, 0.f, 0.f};
  f32x4 acc2[4][4];
  #pragma unroll
  for (int a = 0; a < 4; ++a)
    #pragma unroll
    for (int c = 0; c < 4; ++c) acc2[a][c] = fz;

  const size_t xbase = (((size_t)k * NMTILE + (m0 >> 4) + gm * 4) * 4) * 512 + (size_t)lane * 8;

  #pragma unroll 1
  for (int nc = 0; nc < 4; ++nc) {
    char* const Hc = (nc & 1) ? HsB : HsA;
    const unsigned short* w1b = w1f + (size_t)(k * 4 + nc) * 16384 + lane * 8;

    // ---- fc1 (swapped operands): acc1 = W1frag x Xfrag, all from global ----
    f32x4 acc1[4][2];
    #pragma unroll
    for (int a = 0; a < 4; ++a) { acc1[a][0] = fz; acc1[a][1] = fz; }

    #pragma unroll
    for (int kk = 0; kk < 4; ++kk) {
      short8 wa0 = *(const short8*)(w1b + (gh * 8 + kk) * 512);
      short8 wa1 = *(const short8*)(w1b + (gh * 8 + 4 + kk) * 512);
      #pragma unroll
      for (int m4 = 0; m4 < 4; ++m4) {
        short8 xv = *(const short8*)(xtf + xbase + (m4 * 4 + kk) * 512);
        acc1[m4][0] = mfma_bf16(wa0, xv, acc1[m4][0]);
        acc1[m4][1] = mfma_bf16(wa1, xv, acc1[m4][1]);
      }
    }

    // ---- fc1 epilogue: fold norm, tanh, pack 4 h -> b64 into Hc ----
    const float* t1k = t1p + k * HDIM + nc * 128;
    const float* t2k = t2p + k * HDIM + nc * 128;
    #pragma unroll
    for (int m4 = 0; m4 < 4; ++m4) {
      const int mloc = gm * 64 + m4 * 16 + col;
      const int swz = (mloc & 7) << 4;
      const float rsm = rs4[m4], rmn = rs4[m4] * mn4[m4];
      #pragma unroll
      for (int ht = 0; ht < 2; ++ht) {
        const int hb = gh * 32 + ht * 16 + q4 * 4;
        f32x4 c1 = *(const f32x4*)(t1k + hb);
        f32x4 c2 = *(const f32x4*)(t2k + hb);
        f32x4 v = acc1[m4][ht];
        float e0 = fast_tanh(rsm * v[0] - rmn * c1[0] + c2[0]);
        float e1 = fast_tanh(rsm * v[1] - rmn * c1[1] + c2[1]);
        float e2 = fast_tanh(rsm * v[2] - rmn * c1[2] + c2[2]);
        float e3 = fast_tanh(rsm * v[3] - rmn * c1[3] + c2[3]);
        unsigned long long pk =
            (unsigned long long)f2bf(e0) | ((unsigned long long)f2bf(e1) << 16) |
            ((unsigned long long)f2bf(e2) << 32) | ((unsigned long long)f2bf(e3) << 48);
        *(unsigned long long*)(Hc + mloc * 256 + ((2 * hb) ^ swz)) = pk;
      }
    }

    __syncthreads();   // Hc visible; HsA/HsB alternation makes 1 barrier/nc safe

    // ---- fc2 partial: acc2 += Hfrag x W2frag (W2 from global, frag order) ----
    const unsigned short* w2b = w2f + (size_t)(k * 4 + nc) * 28672 + lane * 8;
    #pragma unroll
    for (int kp = 0; kp < 4; ++kp) {
      const int cb = kp * 64 + q4 * 16;
      short8 ha[4];
      #pragma unroll
      for (int m4 = 0; m4 < 4; ++m4) {
        const int mloc = gm * 64 + m4 * 16 + col;
        ha[m4] = *(const short8*)(Hc + mloc * 256 + (cb ^ ((mloc & 7) << 4)));
      }
      #pragma unroll
      for (int s = 0; s < 4; ++s) {
        const int i = gh + 4 * s;
        if (i < nn) {
          short8 wb = *(const short8*)(w2b + (i * 4 + kp) * 512);
          #pragma unroll
          for (int m4 = 0; m4 < 4; ++m4)
            acc2[m4][s] = mfma_bf16(ha[m4], wb, acc2[m4][s]);
        }
      }
    }
  }

  // ---- output epilogue: bias, GLU via shfl_xor ----
  const float* b2k = b2p + (size_t)k * OPAD;
  const bool plain = ((m0 + 127) / 2000 == m0 / 2000) && (m0 + 128 <= MTOT);
  if (plain) {
    __syncthreads();   // all fc2 reads of Hs done before Ls overwrite
    #pragma unroll
    for (int s = 0; s < 4; ++s) {
      const int i = gh + 4 * s;
      if (i < nn) {
        const int o = i * 16 + col;
        const float bias = b2k[o];
        const bool isA = (o & 1) == 0;
        const int op = o >> 1;
        #pragma unroll
        for (int m4 = 0; m4 < 4; ++m4) {
          f32x4 v = acc2[m4][s];
          #pragma unroll
          for (int r2 = 0; r2 < 4; ++r2) {
            float val = v[r2] + bias;
            float other = __shfl_xor(val, 1);
            if (isA && op < half) {
              int tloc = gm * 64 + m4 * 16 + q4 * 4 + r2;
              int orr = op / 6;
              int occ = op - orr * 6;
              Ls[(orr * 128 + tloc) * 6 + occ] = val * fast_sigmoid(other);
            }
          }
        }
      }
    }
    __syncthreads();
    // coalesced store: per orr a contiguous 3072B run
    const int bb = m0 / 2000;
    const int tb = m0 - bb * 2000;
    const size_t obase = ((size_t)bb * 257 + boffk) * 2000;
    const int tot = bw * 384;          // u64 chunks
    for (int ii = tid; ii < tot; ii += 512) {
      int orr = ii / 384;
      int rem = ii - orr * 384;
      *(unsigned long long*)(out + (obase + (size_t)orr * 2000 + tb) * 6 + rem * 2) =
          *(const unsigned long long*)(Ls + orr * 768 + rem * 2);
    }
  } else {
    // boundary/tail tiles: scatter store
    #pragma unroll
    for (int s = 0; s < 4; ++s) {
      const int i = gh + 4 * s;
      if (i < nn) {
        const int o = i * 16 + col;
        const float bias = b2k[o];
        const bool isA = (o & 1) == 0;
        const int op = o >> 1;
        #pragma unroll
        for (int m4 = 0; m4 < 4; ++m4) {
          f32x4 v = acc2[m4][s];
          #pragma unroll
          for (int r2 = 0; r2 < 4; ++r2) {
            float val = v[r2] + bias;
            float other = __shfl_xor(val, 1);
            int m = m0 + gm * 64 + m4 * 16 + q4 * 4 + r2;
            if (isA && op < half && m < MTOT) {
              float res = val * fast_sigmoid(other);
              int bb = m / 2000;
              int t = m - bb * 2000;
              int orr = op / 6;
              int occ = op - orr * 6;
              out[(((size_t)bb * 257 + boffk + orr) * TDIM + t) * 6 + occ] = res;
            }
          }
        }
      }
    }
  }
}

extern "C" void kernel_launch(void* const* d_in, const int* in_sizes, int n_in,
                              void* d_out, int out_size, void* d_ws, size_t ws_size,
                              hipStream_t stream) {
  const float* x      = (const float*)d_in[0];
  const float* norm_w = (const float*)d_in[1];
  const float* norm_b = (const float*)d_in[2];
  const float* fc1_w  = (const float*)d_in[3];
  const float* fc1_b  = (const float*)d_in[4];
  const float* fc2_w  = (const float*)d_in[5];
  const float* fc2_b  = (const float*)d_in[6];
  float* out = (float*)d_out;
  char* ws = (char*)d_ws;

  float* wsum  = (float*)(ws);
  float* wsq   = (float*)(ws + 512);
  float* gmean = (float*)(ws + 1024);
  float* grstd = (float*)(ws + 1536);
  size_t off = 4096;
  unsigned short* xtf = (unsigned short*)(ws + off); off += (size_t)NBANDS * NMTILE * 4 * 512 * 2;
  unsigned short* w1f = (unsigned short*)(ws + off); off += (size_t)NBANDS * 4 * 8 * 4 * 512 * 2;
  float* t1p = (float*)(ws + off); off += (size_t)NBANDS * HDIM * 4;
  float* t2p = (float*)(ws + off); off += (size_t)NBANDS * HDIM * 4;
  unsigned short* w2f = (unsigned short*)(ws + off); off += (size_t)NBANDS * 4 * 14 * 4 * 512 * 2;
  float* b2p = (float*)(ws + off); off += (size_t)NBANDS * OPAD * 4;

  hipMemsetAsync(ws, 0, 1024, stream);
  hipLaunchKernelGGL(k_prep_w1, dim3(NBANDS * HDIM), dim3(128), 0, stream,
                     fc1_w, norm_w, norm_b, fc1_b, w1f, t1p, t2p);
  hipLaunchKernelGGL(k_prep_w2, dim3(NBANDS * OPAD), dim3(256), 0, stream,
                     fc2_w, fc2_b, w2f, b2p);
  hipLaunchKernelGGL(k_transpose, dim3(250, 4), dim3(256), 0, stream, x, xtf, wsum, wsq);
  hipLaunchKernelGGL(k_finalize, dim3(1), dim3(128), 0, stream, wsum, wsq, gmean, grstd);

  hipFuncSetAttribute((const void*)k_gemm, hipFuncAttributeMaxDynamicSharedMemorySize, 65536);
  hipLaunchKernelGGL(k_gemm, dim3(NWG), dim3(512), 65536, stream,
                     xtf, w1f, t1p, t2p, w2f, b2p, gmean, grstd, out);
}

// Round 6
// 260.462 us; speedup vs baseline: 1.9219x; 1.2320x over previous
//
#include <hip/hip_runtime.h>
#include <hip/hip_bf16.h>

#define NBANDS 31
#define CDIM 128
#define TDIM 2000
#define HDIM 512
#define MTOT 8000
#define MAXO 204
#define OPAD 224       // b2 bias padded length (>= 13*16+16)
#define OT2 16         // padded fc2 o-tiles in w2f (16*16 = 256 rows, zero-filled)
#define NGRP 124
#define NMT 63
#define NWG (NBANDS * NMT)
#define NMTILE 504     // padded 16-row m-tiles per band (63*8 = 504 >= 500)

typedef __attribute__((ext_vector_type(8))) short short8;
typedef __attribute__((ext_vector_type(4))) float f32x4;
typedef __attribute__((ext_vector_type(4))) unsigned int u32x4;
typedef __bf16 bf16x8 __attribute__((ext_vector_type(8)));

__constant__ int d_bw[NBANDS]   = {2,3,3,3,3,3,3,3,3,3,3,8,8,8,8,8,8,8,8,8,8,8,8,16,16,16,16,16,16,16,17};
__constant__ int d_boff[NBANDS] = {0,2,5,8,11,14,17,20,23,26,29,32,40,48,56,64,72,80,88,96,104,112,120,128,144,160,176,192,208,224,240};
__constant__ int d_nn16[NBANDS] = {2,3,3,3,3,3,3,3,3,3,3,6,6,6,6,6,6,6,6,6,6,6,6,12,12,12,12,12,12,12,13};

__device__ __forceinline__ unsigned short f2bf(float f) {
  unsigned int u = __float_as_uint(f);
  return (unsigned short)((u + 0x7fffu + ((u >> 16) & 1u)) >> 16);
}

// packed f32x2 -> bf16x2 (RNE) in one instruction; no builtin on gfx950 (T12)
__device__ __forceinline__ unsigned int cvt_pk_bf16(float lo, float hi) {
  unsigned int r;
  asm("v_cvt_pk_bf16_f32 %0, %1, %2" : "=v"(r) : "v"(lo), "v"(hi));
  return r;
}

// tanh(x) = 1 - 2/(exp2(2*log2e*x)+1): 5 VALU, exact limits at +/-inf
__device__ __forceinline__ float fast_tanh(float x) {
  float p = __builtin_amdgcn_exp2f(2.885390082f * x);
  return 1.0f - 2.0f * __builtin_amdgcn_rcpf(p + 1.0f);
}

// sigmoid(x) = 1/(1+exp2(-log2e*x)): 4 VALU
__device__ __forceinline__ float fast_sigmoid(float x) {
  return __builtin_amdgcn_rcpf(1.0f + __builtin_amdgcn_exp2f(-1.442695041f * x));
}

__device__ __forceinline__ f32x4 mfma_bf16(short8 a, short8 b, f32x4 c) {
  return __builtin_amdgcn_mfma_f32_16x16x32_bf16(
      __builtin_bit_cast(bf16x8, a), __builtin_bit_cast(bf16x8, b), c, 0, 0, 0);
}

// ------------- finalize group stats -------------
__global__ void k_finalize(const float* __restrict__ wsum, const float* __restrict__ wsq,
                           float* __restrict__ gmean, float* __restrict__ grstd) {
  int g = threadIdx.x;
  if (g < NGRP) {
    const float n = (float)(CDIM * TDIM);
    float m = wsum[g] / n;
    float v = wsq[g] / n - m * m;
    gmean[g] = m;
    grstd[g] = rsqrtf(v + 1e-5f);
  }
}

// ------------- prep fc1: fold norm affine, write MFMA-A fragment order ------
// w1f layout: [k][nc 4][hh 8][kk 4][lane 64][8e]; lane l holds
//   W1fold[h = nc*128 + hh*16 + (l&15)][c = kk*32 + (l>>4)*8 + j]
__global__ void k_prep_w1(const float* __restrict__ fc1_w, const float* __restrict__ norm_w,
                          const float* __restrict__ norm_b, const float* __restrict__ fc1_b,
                          unsigned short* __restrict__ w1f, float* __restrict__ t1,
                          float* __restrict__ t2) {
  int kn = blockIdx.x;              // k*512 + n(h)
  int k = kn >> 9, n = kn & 511;
  int c = threadIdx.x;              // 128 threads
  float w  = fc1_w[(size_t)kn * CDIM + c];
  float nw = norm_w[k * CDIM + c];
  float nb = norm_b[k * CDIM + c];
  float wp = w * nw;
  {
    int nc = n >> 7, hh = (n >> 4) & 7, kk = c >> 5;
    int lnw = (n & 15) | (((c >> 3) & 3) << 4);
    size_t eoff = ((((size_t)(k * 4 + nc) * 8 + hh) * 4 + kk) * 64 + lnw) * 8 + (c & 7);
    w1f[eoff] = f2bf(wp);
  }
  float s1 = wp, s2 = w * nb;
  #pragma unroll
  for (int off = 32; off >= 1; off >>= 1) {
    s1 += __shfl_down(s1, off);
    s2 += __shfl_down(s2, off);
  }
  __shared__ float r1[2], r2[2];
  if ((threadIdx.x & 63) == 0) { r1[threadIdx.x >> 6] = s1; r2[threadIdx.x >> 6] = s2; }
  __syncthreads();
  if (threadIdx.x == 0) {
    t1[kn] = r1[0] + r1[1];
    t2[kn] = r2[0] + r2[1] + fc1_b[kn];
  }
}

// ------------- prep fc2: GLU-pair permute, MFMA-B fragment order ------------
// w2f layout: [k][nc 4][iw OT2][kp 4][lane 64][8e]; otile i stored at slot
//   iw = (i&3)*4 + (i>>2) so wave gh's tiles (i = gh+4s) sit at iw = gh*4+s
//   (contiguous 16 KB per wave -> biased-base imm-offset loads).
__global__ void k_prep_w2(const float* __restrict__ fc2_w, const float* __restrict__ fc2_b,
                          unsigned short* __restrict__ w2f, float* __restrict__ b2) {
  int ko = blockIdx.x;              // k*256 + o
  int k = ko >> 8;
  int o = ko & 255;
  int bw = d_bw[k];
  int O2 = 12 * bw, hf = 6 * bw;
  bool valid = o < O2;
  int srcrow = valid ? ((o & 1) ? (hf + (o >> 1)) : (o >> 1)) : 0;
  const float* sp = fc2_w + ((size_t)k * MAXO + srcrow) * HDIM;
  if (threadIdx.x == 0 && o < OPAD)
    b2[k * OPAD + o] = valid ? fc2_b[k * MAXO + srcrow] : 0.f;
  int ot = o >> 4, rr = o & 15;
  int iw = ((ot & 3) << 2) | (ot >> 2);
  for (int j = threadIdx.x; j < HDIM; j += 256) {
    int nc = j >> 7, jc = j & 127, kp = jc >> 5, q = (jc >> 3) & 3, jj = j & 7;
    int lnw = rr | (q << 4);
    unsigned short val = valid ? f2bf(sp[j]) : (unsigned short)0;
    size_t eoff = ((((size_t)(k * 4 + nc) * OT2 + iw) * 4 + kp) * 64 + lnw) * 8 + jj;
    w2f[eoff] = val;
  }
}

// ------------- transpose x[B,C,T,K] -> xtf fragment order, fused stats ------
// xtf layout: [k][mtile NMTILE][kk 4][lane 64][8e]; lane l holds
//   X[m = mtile*16 + (l&15)][c = kk*32 + (l>>4)*8 + j]
__global__ void k_transpose(const float* __restrict__ x, unsigned short* __restrict__ xtf,
                            float* __restrict__ wsum, float* __restrict__ wsq) {
  __shared__ unsigned short tile[248 * 128];   // rows staggered by 4f bytes
  __shared__ float sred[256], sqred[256];
  const int t0 = blockIdx.x * 8;
  const int b = blockIdx.y;
  const int tid = threadIdx.x;
  const float* p = x + ((size_t)b * CDIM * TDIM + t0) * NBANDS;
  float s = 0.f, sq = 0.f;
  if (tid < 248) {
    const int f = tid;
    char* row = (char*)tile + f * 256;
    const int st = 4 * f;
    #pragma unroll 4
    for (int c2 = 0; c2 < 64; ++c2) {
      float v0 = p[(size_t)c2 * 124000 + f];
      float v1 = p[(size_t)c2 * 124000 + 62000 + f];
      s += v0 + v1;
      sq += v0 * v0 + v1 * v1;
      *(unsigned int*)(row + ((4 * c2 + st) & 255)) = cvt_pk_bf16(v0, v1);
    }
  }
  sred[tid] = s; sqred[tid] = sq;
  __syncthreads();
  if (tid < 31) {
    float ss = 0.f, qs = 0.f;
    #pragma unroll
    for (int j = 0; j < 8; ++j) { ss += sred[tid + 31 * j]; qs += sqred[tid + 31 * j]; }
    atomicAdd(&wsum[b * 31 + tid], ss);
    atomicAdd(&wsq [b * 31 + tid], qs);
  }
  // write fragment-ordered, 128B coalesced runs (ti fastest)
  for (int idx = tid; idx < 3968; idx += 256) {
    int ti = idx & 7, q4w = (idx >> 3) & 3, kkw = (idx >> 5) & 3, kb = idx >> 7;
    int f = ti * 31 + kb;
    const char* row = (const char*)tile + f * 256;
    const int st = 4 * f;
    u32x4 v;
    #pragma unroll
    for (int j = 0; j < 4; ++j)
      v[j] = *(const unsigned int*)(row + ((kkw * 64 + q4w * 16 + 4 * j + st) & 255));
    int m = b * TDIM + t0 + ti;
    int mtile = m >> 4, mrow = m & 15;
    size_t eoff = ((((size_t)kb * NMTILE + mtile) * 4 + kkw) * 64 + (mrow | (q4w << 4))) * 8;
    *(u32x4*)(xtf + eoff) = v;
  }
}

// ------------- fused GEMM: fc1 + tanh + fc2 + GLU ---------------------------
// __launch_bounds__(512, 2): 128-VGPR cap, no spill (R5: 124 used).  (512,4)
// caps at 64 and spills ~60 regs -> 520 MB scratch traffic (R4 regression).
__launch_bounds__(512, 2)
__global__ void k_gemm(const unsigned short* __restrict__ xtf,
                       const unsigned short* __restrict__ w1f,
                       const float* __restrict__ t1p, const float* __restrict__ t2p,
                       const unsigned short* __restrict__ w2f,
                       const float* __restrict__ b2p,
                       const float* __restrict__ gmean, const float* __restrict__ grstd,
                       float* __restrict__ out) {
  extern __shared__ char lds[];
  char* const HsA = lds;            // 32 KB [128 m][128 h] swizzled bf16
  char* const HsB = lds + 32768;    // 32 KB
  float* const Ls = (float*)lds;    // out-staging reuse (<= 52.2 KB)

  // bijective XCD-aware swizzle (nwg = 1953)
  const int bid = blockIdx.x;
  const int qq = NWG >> 3, r8 = NWG & 7;
  const int xcd = bid & 7, ixd = bid >> 3;
  const int wg = (xcd < r8 ? xcd * (qq + 1) : r8 * (qq + 1) + (xcd - r8) * qq) + ixd;
  const int k = wg / NMT;
  const int mt = wg - k * NMT;
  const int m0 = mt * 128;

  const int tid = threadIdx.x;
  const int lane = tid & 63;
  const int wid = tid >> 6;
  const int gm = wid & 1;     // m-half (64 rows)
  const int gh = wid >> 1;    // fc1 h-group / fc2 o-slot base
  const int col = lane & 15;
  const int q4 = lane >> 4;

  const int bw = d_bw[k];
  const int nn = d_nn16[k];
  const int half = 6 * bw;
  const int boffk = d_boff[k];
  // wave-uniform fc2 tile count for this wave: tiles i = gh+4s < nn
  const int sWs = __builtin_amdgcn_readfirstlane(gh < nn ? ((nn - gh + 3) >> 2) : 0);

  // per-column norm constants (output col = token)
  float rs4[4], mn4[4];
  #pragma unroll
  for (int m4 = 0; m4 < 4; ++m4) {
    int mr = m0 + gm * 64 + m4 * 16 + col;
    int mc = mr < (MTOT - 1) ? mr : (MTOT - 1);
    int g = (mc / 2000) * NBANDS + k;
    rs4[m4] = grstd[g];
    mn4[m4] = gmean[g];
  }

  const f32x4 fz = {0.f, 0.f, 0.f, 0.f};
  f32x4 acc2[4][4];
  #pragma unroll
  for (int a = 0; a < 4; ++a)
    #pragma unroll
    for (int c = 0; c < 4; ++c) acc2[a][c] = fz;

  // biased X bases: load idx = m4*4+kk at imm offset (idx*1024 - 4096|12288) B
  const size_t xbase = (((size_t)k * NMTILE + (m0 >> 4) + gm * 4) * 4) * 512 + (size_t)lane * 8;
  const unsigned short* const xq0 = xtf + xbase + 2048;
  const unsigned short* const xq1 = xtf + xbase + 6144;

  #pragma unroll 1
  for (int nc = 0; nc < 4; ++nc) {
    char* const Hc = (nc & 1) ? HsB : HsA;

    // ---- fc1 (swapped operands): acc1 = W1frag x Xfrag, all from global ----
    f32x4 acc1[4][2];
    #pragma unroll
    for (int a = 0; a < 4; ++a) { acc1[a][0] = fz; acc1[a][1] = fz; }

    // biased W1 base: 8 loads all at +/-4KB imm offsets
    const unsigned short* const w1q =
        w1f + (size_t)(k * 4 + nc) * 16384 + gh * 4096 + (size_t)lane * 8 + 2048;
    #pragma unroll
    for (int kk = 0; kk < 4; ++kk) {
      short8 wa0 = *(const short8*)(w1q + kk * 512 - 2048);
      short8 wa1 = *(const short8*)(w1q + kk * 512);
      #pragma unroll
      for (int m4 = 0; m4 < 4; ++m4) {
        const int idx = m4 * 4 + kk;
        short8 xv = (idx < 8) ? *(const short8*)(xq0 + idx * 512 - 2048)
                              : *(const short8*)(xq1 + idx * 512 - 6144);
        acc1[m4][0] = mfma_bf16(wa0, xv, acc1[m4][0]);
        acc1[m4][1] = mfma_bf16(wa1, xv, acc1[m4][1]);
      }
    }

    // ---- fc1 epilogue: fold norm, tanh, cvt_pk -> b64 into Hc ----
    const float* t1k = t1p + k * HDIM + nc * 128;
    const float* t2k = t2p + k * HDIM + nc * 128;
    #pragma unroll
    for (int ht = 0; ht < 2; ++ht) {
      const int hb = gh * 32 + ht * 16 + q4 * 4;
      const f32x4 c1 = *(const f32x4*)(t1k + hb);
      const f32x4 c2 = *(const f32x4*)(t2k + hb);
      #pragma unroll
      for (int m4 = 0; m4 < 4; ++m4) {
        const int mloc = gm * 64 + m4 * 16 + col;
        const int swz = (mloc & 7) << 4;
        const float rsm = rs4[m4], rmn = rs4[m4] * mn4[m4];
        f32x4 v = acc1[m4][ht];
        float e0 = fast_tanh(fmaf(rsm, v[0], fmaf(-rmn, c1[0], c2[0])));
        float e1 = fast_tanh(fmaf(rsm, v[1], fmaf(-rmn, c1[1], c2[1])));
        float e2 = fast_tanh(fmaf(rsm, v[2], fmaf(-rmn, c1[2], c2[2])));
        float e3 = fast_tanh(fmaf(rsm, v[3], fmaf(-rmn, c1[3], c2[3])));
        unsigned long long pk = (unsigned long long)cvt_pk_bf16(e0, e1) |
                                ((unsigned long long)cvt_pk_bf16(e2, e3) << 32);
        *(unsigned long long*)(Hc + mloc * 256 + ((2 * hb) ^ swz)) = pk;
      }
    }

    __syncthreads();   // Hc visible; HsA/HsB alternation makes 1 barrier/nc safe

    // ---- fc2 partial: acc2 += Hfrag x W2frag; wave's tiles contiguous ----
    const unsigned short* const wq0 =
        w2f + (size_t)(k * 4 + nc) * 32768 + gh * 8192 + (size_t)lane * 8 + 2048;
    const unsigned short* const wq1 = wq0 + 4096;
    #pragma unroll
    for (int kp = 0; kp < 4; ++kp) {
      const int cb = kp * 64 + q4 * 16;
      short8 ha[4];
      #pragma unroll
      for (int m4 = 0; m4 < 4; ++m4) {
        const int mloc = gm * 64 + m4 * 16 + col;
        ha[m4] = *(const short8*)(Hc + mloc * 256 + (cb ^ ((mloc & 7) << 4)));
      }
      #pragma unroll
      for (int s = 0; s < 4; ++s) {
        if (s < sWs) {
          const int idx = s * 4 + kp;
          short8 wb = (idx < 8) ? *(const short8*)(wq0 + idx * 512 - 2048)
                                : *(const short8*)(wq1 + idx * 512 - 6144);
          #pragma unroll
          for (int m4 = 0; m4 < 4; ++m4)
            acc2[m4][s] = mfma_bf16(ha[m4], wb, acc2[m4][s]);
        }
      }
    }
  }

  // ---- output epilogue: bias, GLU via shfl_xor ----
  const float* b2k = b2p + (size_t)k * OPAD;
  const bool plain = ((m0 + 127) / 2000 == m0 / 2000) && (m0 + 128 <= MTOT);
  if (plain) {
    __syncthreads();   // all fc2 reads of Hs done before Ls overwrite
    #pragma unroll
    for (int s = 0; s < 4; ++s) {
      if (s < sWs) {
        const int o = (gh + 4 * s) * 16 + col;
        const float bias = b2k[o];
        const bool isA = (o & 1) == 0;
        const int op = o >> 1;
        #pragma unroll
        for (int m4 = 0; m4 < 4; ++m4) {
          f32x4 v = acc2[m4][s];
          #pragma unroll
          for (int r2 = 0; r2 < 4; ++r2) {
            float val = v[r2] + bias;
            float other = __shfl_xor(val, 1);
            if (isA && op < half) {
              int tloc = gm * 64 + m4 * 16 + q4 * 4 + r2;
              int orr = op / 6;
              int occ = op - orr * 6;
              Ls[(orr * 128 + tloc) * 6 + occ] = val * fast_sigmoid(other);
            }
          }
        }
      }
    }
    __syncthreads();
    // coalesced store: per orr a contiguous 3072B run
    const int bb = m0 / 2000;
    const int tb = m0 - bb * 2000;
    const size_t obase = ((size_t)bb * 257 + boffk) * 2000;
    const int tot = bw * 384;          // u64 chunks
    for (int ii = tid; ii < tot; ii += 512) {
      int orr = ii / 384;
      int rem = ii - orr * 384;
      *(unsigned long long*)(out + (obase + (size_t)orr * 2000 + tb) * 6 + rem * 2) =
          *(const unsigned long long*)(Ls + orr * 768 + rem * 2);
    }
  } else {
    // boundary/tail tiles: scatter store
    #pragma unroll
    for (int s = 0; s < 4; ++s) {
      if (s < sWs) {
        const int o = (gh + 4 * s) * 16 + col;
        const float bias = b2k[o];
        const bool isA = (o & 1) == 0;
        const int op = o >> 1;
        #pragma unroll
        for (int m4 = 0; m4 < 4; ++m4) {
          f32x4 v = acc2[m4][s];
          #pragma unroll
          for (int r2 = 0; r2 < 4; ++r2) {
            float val = v[r2] + bias;
            float other = __shfl_xor(val, 1);
            int m = m0 + gm * 64 + m4 * 16 + q4 * 4 + r2;
            if (isA && op < half && m < MTOT) {
              float res = val * fast_sigmoid(other);
              int bb = m / 2000;
              int t = m - bb * 2000;
              int orr = op / 6;
              int occ = op - orr * 6;
              out[(((size_t)bb * 257 + boffk + orr) * TDIM + t) * 6 + occ] = res;
            }
          }
        }
      }
    }
  }
}

extern "C" void kernel_launch(void* const* d_in, const int* in_sizes, int n_in,
                              void* d_out, int out_size, void* d_ws, size_t ws_size,
                              hipStream_t stream) {
  const float* x      = (const float*)d_in[0];
  const float* norm_w = (const float*)d_in[1];
  const float* norm_b = (const float*)d_in[2];
  const float* fc1_w  = (const float*)d_in[3];
  const float* fc1_b  = (const float*)d_in[4];
  const float* fc2_w  = (const float*)d_in[5];
  const float* fc2_b  = (const float*)d_in[6];
  float* out = (float*)d_out;
  char* ws = (char*)d_ws;

  float* wsum  = (float*)(ws);
  float* wsq   = (float*)(ws + 512);
  float* gmean = (float*)(ws + 1024);
  float* grstd = (float*)(ws + 1536);
  size_t off = 4096;
  unsigned short* xtf = (unsigned short*)(ws + off); off += (size_t)NBANDS * NMTILE * 4 * 512 * 2;
  unsigned short* w1f = (unsigned short*)(ws + off); off += (size_t)NBANDS * 4 * 8 * 4 * 512 * 2;
  float* t1p = (float*)(ws + off); off += (size_t)NBANDS * HDIM * 4;
  float* t2p = (float*)(ws + off); off += (size_t)NBANDS * HDIM * 4;
  unsigned short* w2f = (unsigned short*)(ws + off); off += (size_t)NBANDS * 4 * OT2 * 4 * 512 * 2;
  float* b2p = (float*)(ws + off); off += (size_t)NBANDS * OPAD * 4;

  hipMemsetAsync(ws, 0, 1024, stream);
  hipLaunchKernelGGL(k_prep_w1, dim3(NBANDS * HDIM), dim3(128), 0, stream,
                     fc1_w, norm_w, norm_b, fc1_b, w1f, t1p, t2p);
  hipLaunchKernelGGL(k_prep_w2, dim3(NBANDS * 256), dim3(256), 0, stream,
                     fc2_w, fc2_b, w2f, b2p);
  hipLaunchKernelGGL(k_transpose, dim3(250, 4), dim3(256), 0, stream, x, xtf, wsum, wsq);
  hipLaunchKernelGGL(k_finalize, dim3(1), dim3(128), 0, stream, wsum, wsq, gmean, grstd);

  hipFuncSetAttribute((const void*)k_gemm, hipFuncAttributeMaxDynamicSharedMemorySize, 65536);
  hipLaunchKernelGGL(k_gemm, dim3(NWG), dim3(512), 65536, stream,
                     xtf, w1f, t1p, t2p, w2f, b2p, gmean, grstd, out);
}